// Round 13
// baseline (59.105 us; speedup 1.0000x reference)
//
#include <hip/hip_runtime.h>
#include <stdint.h>

#define B 4096
#define D 512

// One main dispatch: exactly 2048 blocks (= 256 CUs x 8 resident 256-thread
// blocks, one batch). Block b handles rows r0=2b, 2b+1 end-to-end:
// neg-select (all 4096 cols, thread t owns cols [16t,16t+16)), pos-select
// (exec-masked hashes on the ~16 same-label cols), and the per-row triplet
// loss (wave 0 -> row r0, wave 1 -> row r0+1).
#define NB_NEG 2048

// Rotate-left. Device: single v_alignbit_b32 (rotl d == rotr 32-d).
__host__ __device__ __forceinline__ uint32_t rotl32(uint32_t x, int d) {
#ifdef __HIP_DEVICE_COMPILE__
    return __builtin_amdgcn_alignbit(x, x, (uint32_t)(32 - d));
#else
    return (x << d) | (x >> (32 - d));
#endif
}

// Threefry-2x32, 20 rounds — bit-exact match of jax._src.prng.threefry2x32.
__host__ __device__ __forceinline__ void tf2x32(uint32_t k0, uint32_t k1,
                                                uint32_t x0, uint32_t x1,
                                                uint32_t& o0, uint32_t& o1) {
    const uint32_t k2 = k0 ^ k1 ^ 0x1BD11BDAu;
#define TF_ROUND(r) { x0 += x1; x1 = rotl32(x1, r); x1 ^= x0; }
    x0 += k0; x1 += k1;
    TF_ROUND(13) TF_ROUND(15) TF_ROUND(26) TF_ROUND(6)
    x0 += k1; x1 += k2 + 1u;
    TF_ROUND(17) TF_ROUND(29) TF_ROUND(16) TF_ROUND(24)
    x0 += k2; x1 += k0 + 2u;
    TF_ROUND(13) TF_ROUND(15) TF_ROUND(26) TF_ROUND(6)
    x0 += k0; x1 += k1 + 3u;
    TF_ROUND(17) TF_ROUND(29) TF_ROUND(16) TF_ROUND(24)
    x0 += k1; x1 += k2 + 4u;
    TF_ROUND(13) TF_ROUND(15) TF_ROUND(26) TF_ROUND(6)
    x0 += k2; x1 += k0 + 5u;
#undef TF_ROUND
    o0 = x0; o1 = x1;
}

// JAX partitionable draw for uint32 element `flat`: counter (0, flat), fold.
__device__ __forceinline__ uint32_t draw32(uint32_t k0, uint32_t k1,
                                           uint32_t flat) {
    uint32_t o0, o1;
    tf2x32(k0, k1, 0u, flat, o0, o1);
    return o0 ^ o1;
}

__device__ __forceinline__ unsigned long long umax64(unsigned long long a,
                                                     unsigned long long b) {
    return a > b ? a : b;
}

// Pack (bestv, bestc) so that u64-max == (larger uniform, then smaller col).
// bestv in [0, 2^23); +1 so pack==0 <=> "no candidate".
__device__ __forceinline__ unsigned long long packbest(int bestv, int bestc) {
    return (bestv < 0)
               ? 0ull
               : ((((unsigned long long)(uint32_t)bestv + 1ull) << 12) |
                  (unsigned long long)(uint32_t)(4095 - bestc));
}

// ------------- fused neg-select + pos-select + loss (2 rows/block) -------
__global__ __launch_bounds__(256) void fused_kernel(
        const float* __restrict__ E, const int* __restrict__ labels,
        float* __restrict__ tl, uint32_t kp0, uint32_t kp1, uint32_t kn0,
        uint32_t kn1) {
    __shared__ unsigned long long redn[2][4];
    __shared__ unsigned long long redp[2][4];
    __shared__ int sidx[4];  // [0..1]=ip for rows 0..1, [2..3]=in

    const int bid = blockIdx.x;
    const int t = threadIdx.x;
    const int lane = t & 63;
    const int w = t >> 6;

    const int r0 = bid * 2;
    const int4* lp = (const int4*)(labels + (t << 4));
    const int4 La = lp[0], Lb = lp[1], Lc = lp[2], Ld = lp[3];
    const int lab16[16] = {La.x, La.y, La.z, La.w, Lb.x, Lb.y, Lb.z, Lb.w,
                           Lc.x, Lc.y, Lc.z, Lc.w, Ld.x, Ld.y, Ld.z, Ld.w};
    const int labr0 = labels[r0];
    const int labr1 = labels[r0 + 1];
    const uint32_t f0 = ((uint32_t)r0 << 12) + ((uint32_t)t << 4);

    // ---- negative selection (proven r12 loop, fully unrolled) ----
    int bv0 = -1, bc0 = 0, bv1 = -1, bc1 = 0;
#pragma unroll
    for (int j = 0; j < 16; ++j) {
        const int c = (t << 4) + j;
        const uint32_t h0 = draw32(kn0, kn1, f0 + (uint32_t)j);
        const uint32_t h1 = draw32(kn0, kn1, f0 + (uint32_t)j + 4096u);
        const int v0 = (int)(h0 >> 9);
        const int v1 = (int)(h1 >> 9);
        if ((lab16[j] != labr0) & (v0 > bv0)) { bv0 = v0; bc0 = c; }
        if ((lab16[j] != labr1) & (v1 > bv1)) { bv1 = v1; bc1 = c; }
    }

    // ---- positive selection: hash only same-label cols (exec-masked).
    // Loop kept rolled (unroll 1): rare body, keep I-footprint small. ----
    int pv0 = -1, pc0 = 0, pv1 = -1, pc1 = 0;
#pragma unroll 1
    for (int j = 0; j < 16; ++j) {
        const int c = (t << 4) + j;
        const bool m0 = (lab16[j] == labr0) && (c != r0);
        const bool m1 = (lab16[j] == labr1) && (c != r0 + 1);
        if (m0) {
            const uint32_t h = draw32(kp0, kp1, f0 + (uint32_t)j);
            const int v = (int)(h >> 9);
            if (v > pv0) { pv0 = v; pc0 = c; }
        }
        if (m1) {
            const uint32_t h = draw32(kp0, kp1, f0 + (uint32_t)j + 4096u);
            const int v = (int)(h >> 9);
            if (v > pv1) { pv1 = v; pc1 = c; }
        }
    }

    // ---- cross-lane then cross-wave reductions (u64 pack, proven) ----
    unsigned long long n0 = packbest(bv0, bc0);
    unsigned long long n1 = packbest(bv1, bc1);
    unsigned long long q0 = packbest(pv0, pc0);
    unsigned long long q1 = packbest(pv1, pc1);
#pragma unroll
    for (int off = 32; off > 0; off >>= 1) {
        n0 = umax64(n0, __shfl_down(n0, off));
        n1 = umax64(n1, __shfl_down(n1, off));
        q0 = umax64(q0, __shfl_down(q0, off));
        q1 = umax64(q1, __shfl_down(q1, off));
    }
    if (lane == 0) {
        redn[0][w] = n0; redn[1][w] = n1;
        redp[0][w] = q0; redp[1][w] = q1;
    }
    __syncthreads();
    if (t < 2) {
        unsigned long long bn = redn[t][0];
        unsigned long long bp = redp[t][0];
#pragma unroll
        for (int k = 1; k < 4; ++k) {
            bn = umax64(bn, redn[t][k]);
            bp = umax64(bp, redp[t][k]);
        }
        sidx[t] = bp ? (int)(4095u - (uint32_t)(bp & 0xFFFull)) : -1;
        sidx[2 + t] = bn ? (int)(4095u - (uint32_t)(bn & 0xFFFull)) : -1;
    }
    __syncthreads();

    // ---- loss: wave 0 -> row r0, wave 1 -> row r0+1 (proven r12 body) ----
    if (w < 2) {
        const int r = r0 + w;
        const int ip = sidx[w];
        const int in_ = sidx[2 + w];
        const float4* er = (const float4*)(E + (size_t)r * D);
        float4 a0 = er[lane * 2];
        float4 a1 = er[lane * 2 + 1];
        float aa = a0.x * a0.x + a0.y * a0.y + a0.z * a0.z + a0.w * a0.w +
                   a1.x * a1.x + a1.y * a1.y + a1.z * a1.z + a1.w * a1.w;
        float dp = 0.f, pp = 0.f, dn = 0.f, nn = 0.f;
        if (ip >= 0) {
            const float4* ep = (const float4*)(E + (size_t)ip * D);
            float4 b0 = ep[lane * 2];
            float4 b1 = ep[lane * 2 + 1];
            dp = a0.x * b0.x + a0.y * b0.y + a0.z * b0.z + a0.w * b0.w +
                 a1.x * b1.x + a1.y * b1.y + a1.z * b1.z + a1.w * b1.w;
            pp = b0.x * b0.x + b0.y * b0.y + b0.z * b0.z + b0.w * b0.w +
                 b1.x * b1.x + b1.y * b1.y + b1.z * b1.z + b1.w * b1.w;
        }
        if (in_ >= 0) {
            const float4* en = (const float4*)(E + (size_t)in_ * D);
            float4 c0 = en[lane * 2];
            float4 c1 = en[lane * 2 + 1];
            dn = a0.x * c0.x + a0.y * c0.y + a0.z * c0.z + a0.w * c0.w +
                 a1.x * c1.x + a1.y * c1.y + a1.z * c1.z + a1.w * c1.w;
            nn = c0.x * c0.x + c0.y * c0.y + c0.z * c0.z + c0.w * c0.w +
                 c1.x * c1.x + c1.y * c1.y + c1.z * c1.z + c1.w * c1.w;
        }
#pragma unroll
        for (int off = 32; off > 0; off >>= 1) {
            aa += __shfl_down(aa, off);
            dp += __shfl_down(dp, off);
            pp += __shfl_down(pp, off);
            dn += __shfl_down(dn, off);
            nn += __shfl_down(nn, off);
        }
        if (lane == 0) {
            const float pd = (ip >= 0) ? fmaxf(aa + pp - 2.0f * dp, 0.f) : 0.f;
            const float nd = (in_ >= 0) ? fmaxf(aa + nn - 2.0f * dn, 0.f) : 0.f;
            tl[r] = fmaxf(pd - nd + 1.0f, 0.f);
        }
    }
}

// ---------------- deterministic final reduction ----------------
__global__ __launch_bounds__(256) void finalize_kernel(
        const float* __restrict__ tl, float* __restrict__ out) {
    const int t = threadIdx.x;
    float s = 0.f;
    int c = 0;
    for (int j = t; j < B; j += 256) {
        const float v = tl[j];
        s += v;
        if (v > 1e-16f) c++;
    }
#pragma unroll
    for (int off = 32; off > 0; off >>= 1) {
        s += __shfl_down(s, off);
        c += __shfl_down(c, off);
    }
    __shared__ float ss[4];
    __shared__ int sc[4];
    if ((t & 63) == 0) { ss[t >> 6] = s; sc[t >> 6] = c; }
    __syncthreads();
    if (t == 0) {
#pragma unroll
        for (int k = 1; k < 4; ++k) { s += ss[k]; c += sc[k]; }
        out[0] = (c == 0) ? 0.0f : s * (1.0f / 4096.0f);
    }
}

extern "C" void kernel_launch(void* const* d_in, const int* in_sizes, int n_in,
                              void* d_out, int out_size, void* d_ws,
                              size_t ws_size, hipStream_t stream) {
    const float* E = (const float*)d_in[0];
    const int* labels = (const int*)d_in[1];
    float* out = (float*)d_out;

    float* tl = (float*)d_ws;  // 16 KB

    // Host-side key derivation (matches jax.random.split of key(42),
    // jax_threefry_partitionable=True; verified bit-exact in round 1).
    uint32_t kp0, kp1, kn0, kn1;
    tf2x32(0u, 42u, 0u, 0u, kp0, kp1);
    tf2x32(0u, 42u, 0u, 1u, kn0, kn1);

    fused_kernel<<<NB_NEG, 256, 0, stream>>>(E, labels, tl, kp0, kp1, kn0,
                                             kn1);
    finalize_kernel<<<1, 256, 0, stream>>>(tl, out);
}

// Round 14
// 47.178 us; speedup vs baseline: 1.2528x; 1.2528x over previous
//
#include <hip/hip_runtime.h>
#include <stdint.h>

#define B 4096
#define D 512

// Kernel A: exactly 2048 blocks (= 256 CUs x 8 resident 256-thread blocks,
// one dispatch batch). Block b: negative-selection for rows 2b, 2b+1
// (thread t owns cols [16t, 16t+16)). Block 0 additionally builds the
// label buckets to global memory first (~3 us, hidden under the ~20 us W).
#define NB_NEG 2048

// Rotate-left. Device: single v_alignbit_b32 (rotl d == rotr 32-d).
__host__ __device__ __forceinline__ uint32_t rotl32(uint32_t x, int d) {
#ifdef __HIP_DEVICE_COMPILE__
    return __builtin_amdgcn_alignbit(x, x, (uint32_t)(32 - d));
#else
    return (x << d) | (x >> (32 - d));
#endif
}

// Threefry-2x32, 20 rounds — bit-exact match of jax._src.prng.threefry2x32.
__host__ __device__ __forceinline__ void tf2x32(uint32_t k0, uint32_t k1,
                                                uint32_t x0, uint32_t x1,
                                                uint32_t& o0, uint32_t& o1) {
    const uint32_t k2 = k0 ^ k1 ^ 0x1BD11BDAu;
#define TF_ROUND(r) { x0 += x1; x1 = rotl32(x1, r); x1 ^= x0; }
    x0 += k0; x1 += k1;
    TF_ROUND(13) TF_ROUND(15) TF_ROUND(26) TF_ROUND(6)
    x0 += k1; x1 += k2 + 1u;
    TF_ROUND(17) TF_ROUND(29) TF_ROUND(16) TF_ROUND(24)
    x0 += k2; x1 += k0 + 2u;
    TF_ROUND(13) TF_ROUND(15) TF_ROUND(26) TF_ROUND(6)
    x0 += k0; x1 += k1 + 3u;
    TF_ROUND(17) TF_ROUND(29) TF_ROUND(16) TF_ROUND(24)
    x0 += k1; x1 += k2 + 4u;
    TF_ROUND(13) TF_ROUND(15) TF_ROUND(26) TF_ROUND(6)
    x0 += k2; x1 += k0 + 5u;
#undef TF_ROUND
    o0 = x0; o1 = x1;
}

// JAX partitionable draw for uint32 element `flat`: counter (0, flat), fold.
__device__ __forceinline__ uint32_t draw32(uint32_t k0, uint32_t k1,
                                           uint32_t flat) {
    uint32_t o0, o1;
    tf2x32(k0, k1, 0u, flat, o0, o1);
    return o0 ^ o1;
}

__device__ __forceinline__ unsigned long long umax64(unsigned long long a,
                                                     unsigned long long b) {
    return a > b ? a : b;
}

// Pack (bestv, bestc) so that u64-max == (larger uniform, then smaller col).
// bestv in [0, 2^23); +1 so pack==0 <=> "no candidate".
__device__ __forceinline__ unsigned long long packbest(int bestv, int bestc) {
    return (bestv < 0)
               ? 0ull
               : ((((unsigned long long)(uint32_t)bestv + 1ull) << 12) |
                  (unsigned long long)(uint32_t)(4095 - bestc));
}

// ---------------- Kernel A: neg-select (+ block-0 bucket build) ----------
__global__ __launch_bounds__(256) void neg_bucket_kernel(
        const int* __restrict__ labels, int* __restrict__ idxn,
        int* __restrict__ bstart, unsigned short* __restrict__ bcols,
        uint32_t kn0, uint32_t kn1) {
    __shared__ int cnt[256];
    __shared__ int basex[256];
    __shared__ int fillc[256];
    __shared__ unsigned long long red[2][4];

    const int bid = blockIdx.x;
    const int t = threadIdx.x;
    const int lane = t & 63;
    const int w = t >> 6;

    if (bid == 0) {
        // ---- build label buckets to global (order within bucket free) ----
        const int4* lp = (const int4*)(labels + (t << 4));
        const int4 La = lp[0], Lb = lp[1], Lc = lp[2], Ld = lp[3];
        const int lab16[16] = {La.x, La.y, La.z, La.w, Lb.x, Lb.y, Lb.z, Lb.w,
                               Lc.x, Lc.y, Lc.z, Lc.w, Ld.x, Ld.y, Ld.z, Ld.w};
        cnt[t] = 0;
        fillc[t] = 0;
        __syncthreads();
#pragma unroll
        for (int j = 0; j < 16; ++j) atomicAdd(&cnt[lab16[j]], 1);
        __syncthreads();
        basex[t] = cnt[t];
        __syncthreads();
        for (int off = 1; off < 256; off <<= 1) {
            const int u = (t >= off) ? basex[t - off] : 0;
            __syncthreads();
            basex[t] += u;
            __syncthreads();
        }
        bstart[t] = basex[t] - cnt[t];
        if (t == 255) bstart[256] = B;
#pragma unroll
        for (int j = 0; j < 16; ++j) {
            const int l = lab16[j];
            const int off = atomicAdd(&fillc[l], 1);
            bcols[basex[l] - cnt[l] + off] = (unsigned short)((t << 4) + j);
        }
        __syncthreads();
    }

    // ---- negative selection: 2 rows, thread owns cols [16t, 16t+16) ----
    const int r0 = bid * 2;
    const int4* lp = (const int4*)(labels + (t << 4));
    const int4 La = lp[0], Lb = lp[1], Lc = lp[2], Ld = lp[3];
    const int lab16[16] = {La.x, La.y, La.z, La.w, Lb.x, Lb.y, Lb.z, Lb.w,
                           Lc.x, Lc.y, Lc.z, Lc.w, Ld.x, Ld.y, Ld.z, Ld.w};
    const int labr0 = labels[r0];
    const int labr1 = labels[r0 + 1];
    const uint32_t f0 = ((uint32_t)r0 << 12) + ((uint32_t)t << 4);
    int bv0 = -1, bc0 = 0, bv1 = -1, bc1 = 0;
#pragma unroll
    for (int j = 0; j < 16; ++j) {
        const int c = (t << 4) + j;
        const uint32_t h0 = draw32(kn0, kn1, f0 + (uint32_t)j);
        const uint32_t h1 = draw32(kn0, kn1, f0 + (uint32_t)j + 4096u);
        const int v0 = (int)(h0 >> 9);
        const int v1 = (int)(h1 >> 9);
        if ((lab16[j] != labr0) & (v0 > bv0)) { bv0 = v0; bc0 = c; }
        if ((lab16[j] != labr1) & (v1 > bv1)) { bv1 = v1; bc1 = c; }
    }
    unsigned long long p0 = packbest(bv0, bc0);
    unsigned long long p1 = packbest(bv1, bc1);
#pragma unroll
    for (int off = 32; off > 0; off >>= 1) {
        p0 = umax64(p0, __shfl_down(p0, off));
        p1 = umax64(p1, __shfl_down(p1, off));
    }
    if (lane == 0) { red[0][w] = p0; red[1][w] = p1; }
    __syncthreads();
    if (t < 2) {
        unsigned long long best = red[t][0];
#pragma unroll
        for (int k = 1; k < 4; ++k) best = umax64(best, red[t][k]);
        idxn[r0 + t] = best ? (int)(4095u - (uint32_t)(best & 0xFFFull)) : -1;
    }
}

// -------- Kernel B: pos-select (from buckets) + triplet loss per row ------
// 4 rows per block, one wave per row.
__global__ __launch_bounds__(256) void loss_kernel(
        const float* __restrict__ E, const int* __restrict__ labels,
        const int* __restrict__ bstart, const unsigned short* __restrict__ bcols,
        const int* __restrict__ idxn, float* __restrict__ tl,
        uint32_t kp0, uint32_t kp1) {
    const int lane = threadIdx.x & 63;
    const int w = threadIdx.x >> 6;
    const int r = blockIdx.x * 4 + w;

    // --- positive selection over this row's label bucket (~16 entries) ---
    const int l = labels[r];
    const int s0 = bstart[l];
    const int s1 = bstart[l + 1];
    const uint32_t rbase = (uint32_t)r << 12;
    unsigned long long best = 0ull;
    for (int i = s0 + lane; i < s1; i += 64) {
        const int c = (int)bcols[i];
        if (c == r) continue;
        const uint32_t bits = draw32(kp0, kp1, rbase + (uint32_t)c);
        const unsigned long long pack =
            ((((unsigned long long)(bits >> 9)) + 1ull) << 12) |
            (unsigned long long)(uint32_t)(4095 - c);
        best = umax64(best, pack);
    }
#pragma unroll
    for (int off = 32; off > 0; off >>= 1)
        best = umax64(best, __shfl_xor(best, off));
    const int ip = best ? (int)(4095u - (uint32_t)(best & 0xFFFull)) : -1;
    const int in_ = idxn[r];

    // --- distances: norms computed inline (no sq array) ---
    const float4* er = (const float4*)(E + (size_t)r * D);
    float4 a0 = er[lane * 2];
    float4 a1 = er[lane * 2 + 1];
    float aa = a0.x * a0.x + a0.y * a0.y + a0.z * a0.z + a0.w * a0.w +
               a1.x * a1.x + a1.y * a1.y + a1.z * a1.z + a1.w * a1.w;
    float dp = 0.f, pp = 0.f, dn = 0.f, nn = 0.f;
    if (ip >= 0) {
        const float4* ep = (const float4*)(E + (size_t)ip * D);
        float4 b0 = ep[lane * 2];
        float4 b1 = ep[lane * 2 + 1];
        dp = a0.x * b0.x + a0.y * b0.y + a0.z * b0.z + a0.w * b0.w +
             a1.x * b1.x + a1.y * b1.y + a1.z * b1.z + a1.w * b1.w;
        pp = b0.x * b0.x + b0.y * b0.y + b0.z * b0.z + b0.w * b0.w +
             b1.x * b1.x + b1.y * b1.y + b1.z * b1.z + b1.w * b1.w;
    }
    if (in_ >= 0) {
        const float4* en = (const float4*)(E + (size_t)in_ * D);
        float4 c0 = en[lane * 2];
        float4 c1 = en[lane * 2 + 1];
        dn = a0.x * c0.x + a0.y * c0.y + a0.z * c0.z + a0.w * c0.w +
             a1.x * c1.x + a1.y * c1.y + a1.z * c1.z + a1.w * c1.w;
        nn = c0.x * c0.x + c0.y * c0.y + c0.z * c0.z + c0.w * c0.w +
             c1.x * c1.x + c1.y * c1.y + c1.z * c1.z + c1.w * c1.w;
    }
#pragma unroll
    for (int off = 32; off > 0; off >>= 1) {
        aa += __shfl_down(aa, off);
        dp += __shfl_down(dp, off);
        pp += __shfl_down(pp, off);
        dn += __shfl_down(dn, off);
        nn += __shfl_down(nn, off);
    }
    if (lane == 0) {
        const float pd = (ip >= 0) ? fmaxf(aa + pp - 2.0f * dp, 0.f) : 0.f;
        const float nd = (in_ >= 0) ? fmaxf(aa + nn - 2.0f * dn, 0.f) : 0.f;
        tl[r] = fmaxf(pd - nd + 1.0f, 0.f);
    }
}

// ---------------- Kernel C: deterministic final reduction ----------------
__global__ __launch_bounds__(256) void finalize_kernel(
        const float* __restrict__ tl, float* __restrict__ out) {
    const int t = threadIdx.x;
    float s = 0.f;
    int c = 0;
    for (int j = t; j < B; j += 256) {
        const float v = tl[j];
        s += v;
        if (v > 1e-16f) c++;
    }
#pragma unroll
    for (int off = 32; off > 0; off >>= 1) {
        s += __shfl_down(s, off);
        c += __shfl_down(c, off);
    }
    __shared__ float ss[4];
    __shared__ int sc[4];
    if ((t & 63) == 0) { ss[t >> 6] = s; sc[t >> 6] = c; }
    __syncthreads();
    if (t == 0) {
#pragma unroll
        for (int k = 1; k < 4; ++k) { s += ss[k]; c += sc[k]; }
        out[0] = (c == 0) ? 0.0f : s * (1.0f / 4096.0f);
    }
}

extern "C" void kernel_launch(void* const* d_in, const int* in_sizes, int n_in,
                              void* d_out, int out_size, void* d_ws,
                              size_t ws_size, hipStream_t stream) {
    const float* E = (const float*)d_in[0];
    const int* labels = (const int*)d_in[1];
    float* out = (float*)d_out;

    char* ws = (char*)d_ws;
    int* idxn = (int*)(ws);                          // 16 KB
    float* tl = (float*)(ws + 16384);                // 16 KB
    int* bstart = (int*)(ws + 32768);                // 257 ints
    unsigned short* bcols = (unsigned short*)(ws + 36864);  // 8 KB

    // Host-side key derivation (matches jax.random.split of key(42),
    // jax_threefry_partitionable=True; verified bit-exact in round 1).
    uint32_t kp0, kp1, kn0, kn1;
    tf2x32(0u, 42u, 0u, 0u, kp0, kp1);
    tf2x32(0u, 42u, 0u, 1u, kn0, kn1);

    neg_bucket_kernel<<<NB_NEG, 256, 0, stream>>>(labels, idxn, bstart, bcols,
                                                  kn0, kn1);
    loss_kernel<<<B / 4, 256, 0, stream>>>(E, labels, bstart, bcols, idxn, tl,
                                           kp0, kp1);
    finalize_kernel<<<1, 256, 0, stream>>>(tl, out);
}